// Round 2
// baseline (955.503 us; speedup 1.0000x reference)
//
#include <hip/hip_runtime.h>
#include <hip/hip_bf16.h>
#include <cstdint>
#include <cstddef>

// ---- problem constants ----
#define B_   2
#define S_   4096
#define HIDN 2048
#define H_   16
#define D_   128
#define NB_  64
#define MTOT 8192              // B_*S_
#define SCALE_ 0.08838834764831845f   // 128^-0.5

typedef unsigned short ushort_t;
typedef __attribute__((ext_vector_type(8))) short short8;
typedef __attribute__((ext_vector_type(8))) ushort_t ushort8;
typedef __attribute__((ext_vector_type(4))) float f32x4;

__device__ inline float b2f(ushort_t x){ union{unsigned u; float f;} v; v.u=((unsigned)x)<<16; return v.f; }
__device__ inline ushort_t f2b(float f){ union{unsigned u; float f;} v; v.f=f; unsigned r=(v.u + 0x7FFF + ((v.u>>16)&1))>>16; return (ushort_t)r; }

#define MFMA_BF16(a,b,c) __builtin_amdgcn_mfma_f32_16x16x32_bf16((a),(b),(c),0,0,0)

// async global->LDS, 16B per lane. LDS dest = wave-uniform base + lane*16.
__device__ inline void async16(const ushort_t* g, ushort_t* l){
  __builtin_amdgcn_global_load_lds(
      (const __attribute__((address_space(1))) void*)g,
      (__attribute__((address_space(3))) void*)l, 16, 0, 0);
}

// ---------------- fp32 -> bf16 bulk convert (8 elts/thread) ----------------
__global__ void bsa_convert(const float* __restrict__ x, ushort_t* __restrict__ y){
  size_t i = ((size_t)blockIdx.x*256 + threadIdx.x)*8;
  float4 v0 = *(const float4*)(x+i);
  float4 v1 = *(const float4*)(x+i+4);
  ushort8 o;
  o[0]=f2b(v0.x); o[1]=f2b(v0.y); o[2]=f2b(v0.z); o[3]=f2b(v0.w);
  o[4]=f2b(v1.x); o[5]=f2b(v1.y); o[6]=f2b(v1.z); o[7]=f2b(v1.w);
  *(ushort8*)(y+i) = o;
}

// ---------------- router stage 1: partial column sums over S (fp32 in) ------
// grid (8, 32, 2), block 256. part[(b*32+sc)*HIDN + c] = sum of 128 rows.
__global__ void bsa_partial(const float* __restrict__ hs, float* __restrict__ part){
  int t = threadIdx.x;
  int c = blockIdx.x*256 + t;
  int sc = blockIdx.y;
  int b  = blockIdx.z;
  const float* p = hs + ((size_t)b*S_ + (size_t)sc*128)*HIDN + c;
  float s = 0.f;
  #pragma unroll 8
  for (int i=0;i<128;i++) s += p[(size_t)i*HIDN];
  part[((b*32+sc)*HIDN)+c] = s;
}

// ---------------- router stage 2, single block (all fp32) ----------------
__global__ void bsa_router(const float* __restrict__ part, const float* __restrict__ Wr,
                           const float* __restrict__ br, int* __restrict__ counts){
  __shared__ float cm[2*HIDN];    // 16 KB column means
  __shared__ float sig[2*H_];
  int t = threadIdx.x;
  for (int i=t; i<2*HIDN; i+=256){
    int b = i>>11, c = i&(HIDN-1);
    float s=0.f;
    for (int j=0;j<32;j++) s += part[((b*32+j)*HIDN)+c];
    cm[b*HIDN+c] = s * (1.0f/S_);
  }
  __syncthreads();
  {
    int g = t>>3;        // 0..31 = b*16+h
    int sl = t&7;
    int b = g>>4, h = g&15;
    float acc = 0.f;
    for (int c=sl; c<HIDN; c+=8) acc += cm[b*HIDN+c]*Wr[c*H_+h];
    acc += __shfl_xor(acc, 4);
    acc += __shfl_xor(acc, 2);
    acc += __shfl_xor(acc, 1);
    if (sl==0) sig[g] = 1.f/(1.f+expf(-(acc + br[h])));
  }
  __syncthreads();
  if (t < H_){
    float score = 0.5f*(sig[t] + sig[H_+t]);
    float eff = 0.5f*(1.0f - score*0.5f);
    int ac = (int)floorf(64.f*eff);
    if (ac < 1) ac = 1;
    counts[t] = ac;
  }
}

// ------------- weight transpose+convert: fp32 [K,N] -> bf16 [N,K] -----------
// grid (32,32,4), block 256
__global__ void bsa_transpose(const float* w0, const float* w1, const float* w2, const float* w3,
                              ushort_t* o0, ushort_t* o1, ushort_t* o2, ushort_t* o3){
  const float* src; ushort_t* dst;
  switch(blockIdx.z){
    case 0: src=w0; dst=o0; break;
    case 1: src=w1; dst=o1; break;
    case 2: src=w2; dst=o2; break;
    default: src=w3; dst=o3; break;
  }
  __shared__ ushort_t tile[64*72];   // pad 72 to break bank alignment
  int t = threadIdx.x;
  int r0 = blockIdx.y*64, c0 = blockIdx.x*64;
  for (int it=0; it<16; it++){
    int f = it*256 + t;
    int r = f>>6, c = f&63;
    tile[r*72+c] = f2b(src[(size_t)(r0+r)*HIDN + (c0+c)]);
  }
  __syncthreads();
  for (int it=0; it<16; it++){
    int f = it*256 + t;
    int cc = f>>6, rr = f&63;
    dst[(size_t)(c0+cc)*HIDN + (r0+rr)] = tile[rr*72+cc];
  }
}

// ---------------- m97-style bf16 GEMM: C[M,N] = A[M,K] @ BT[N,K]^T ----------
// 128x128 tile, BK=32, 256 threads = 4 waves (2x2), each wave 4x4 frags of 16x16x32.
// F32OUT: store fp32 accumulator directly; else round to bf16.
template<int F32OUT>
__global__ __launch_bounds__(256) void bsa_gemm_bt(const ushort_t* __restrict__ A,
                                                   const ushort_t* __restrict__ BT,
                                                   void* __restrict__ Cv,
                                                   int M, int N, int K){
  __shared__ __align__(16) ushort_t As[128*32];   // [row][k] 64B rows
  __shared__ __align__(16) ushort_t Bs[128*32];
  int t = threadIdx.x;
  int w = t>>6, lane = t&63;
  int wr = w>>1, wc = w&1;
  int quad = lane>>4, l16 = lane&15;
  int m0 = blockIdx.y*128, n0 = blockIdx.x*128;

  f32x4 acc[4][4] = {};

  // staging: chunk = w*2+i; lane covers LDS elems chunk*512 + lane*8
  // = row (chunk*16 + lane/4), col (lane&3)*8  in the [128][32] tile
  int srow = (w*2)*16 + (lane>>2);
  int scol = (lane&3)*8;

  for (int k0=0; k0<K; k0+=32){
    #pragma unroll
    for (int i=0;i<2;i++){
      int chunk = w*2+i;
      const ushort_t* ga = A  + (size_t)(m0 + srow + i*16)*K + k0 + scol;
      const ushort_t* gb = BT + (size_t)(n0 + srow + i*16)*K + k0 + scol;
      async16(ga, &As[chunk*512]);
      async16(gb, &Bs[chunk*512]);
    }
    __syncthreads();
    short8 a[4], b[4];
    #pragma unroll
    for (int i=0;i<4;i++)
      a[i] = *(const short8*)(&As[(wr*64 + i*16 + l16)*32 + quad*8]);
    #pragma unroll
    for (int j=0;j<4;j++)
      b[j] = *(const short8*)(&Bs[(wc*64 + j*16 + l16)*32 + quad*8]);
    #pragma unroll
    for (int i=0;i<4;i++)
      #pragma unroll
      for (int j=0;j<4;j++)
        acc[i][j] = MFMA_BF16(a[i], b[j], acc[i][j]);
    __syncthreads();
  }

  #pragma unroll
  for (int i=0;i<4;i++)
    #pragma unroll
    for (int j=0;j<4;j++){
      int m = m0 + wr*64 + i*16 + quad*4;
      int n = n0 + wc*64 + j*16 + l16;
      #pragma unroll
      for (int r=0;r<4;r++){
        if (F32OUT) ((float*)Cv)[(size_t)(m+r)*N + n] = acc[i][j][r];
        else        ((ushort_t*)Cv)[(size_t)(m+r)*N + n] = f2b(acc[i][j][r]);
      }
    }
}

// ---------------- block-diagonal top-k attention ----------------
// grid 2048 = B*H*NB, block 256 (4 waves). Tiles 64x128 (Q,K,V), scores 64x64.
// O may alias Q (O written only after Q fully staged to LDS; blocks disjoint).
__global__ __launch_bounds__(256) void bsa_attn(const ushort_t* __restrict__ Q,
                                                const ushort_t* __restrict__ K,
                                                const ushort_t* __restrict__ V,
                                                const int* __restrict__ counts,
                                                ushort_t* __restrict__ O){
  __shared__ __align__(16) ushort_t QV[64*136];  // Q, later reused for V (stride 136)
  __shared__ __align__(16) ushort_t Ks[64*136];
  __shared__ __align__(16) float    Sc[64*68];   // fp32 scores (stride 68)
  __shared__ __align__(16) ushort_t Ps[64*72];   // bf16 probs (stride 72)

  int t = threadIdx.x, w = t>>6, lane = t&63, quad = lane>>4, l16 = lane&15;
  int bid = blockIdx.x;
  int b  = bid>>10;          // /(H_*NB_)
  int h  = (bid>>6)&15;
  int nb = bid&63;
  size_t base = ((size_t)b*S_ + (size_t)nb*64)*HIDN + (size_t)h*D_;

  // stage Q and K tiles
  #pragma unroll
  for (int it=0; it<4; it++){
    int f = it*256 + t;            // 0..1023, 8 bf16 each
    int r = f>>4, c = (f&15)*8;
    *(int4*)(&QV[r*136+c]) = *(const int4*)(Q + base + (size_t)r*HIDN + c);
    *(int4*)(&Ks[r*136+c]) = *(const int4*)(K + base + (size_t)r*HIDN + c);
  }
  __syncthreads();

  // S = Q K^T * scale ; wave w owns query rows 16w..16w+15
  f32x4 sacc[4] = {};
  #pragma unroll
  for (int ks=0; ks<4; ks++){
    short8 afr = *(const short8*)(&QV[(w*16 + l16)*136 + ks*32 + quad*8]);
    #pragma unroll
    for (int nt=0; nt<4; nt++){
      short8 bfr = *(const short8*)(&Ks[(nt*16 + l16)*136 + ks*32 + quad*8]);
      sacc[nt] = MFMA_BF16(afr, bfr, sacc[nt]);
    }
  }
  #pragma unroll
  for (int nt=0; nt<4; nt++)
    #pragma unroll
    for (int r=0;r<4;r++)
      Sc[(w*16 + quad*4 + r)*68 + nt*16 + l16] = sacc[nt][r]*SCALE_;
  __syncthreads();

  // stage V into QV region (all QV reads completed before the barrier above)
  #pragma unroll
  for (int it=0; it<4; it++){
    int f = it*256 + t;
    int r = f>>4, c = (f&15)*8;
    *(int4*)(&QV[r*136+c]) = *(const int4*)(V + base + (size_t)r*HIDN + c);
  }

  // exact stable-descending rank (ties by index) + masked softmax
  int cnt = counts[h];
  for (int rr=0; rr<16; rr++){
    int row = w*16 + rr;
    float s = Sc[row*68 + lane];
    int rank = 0;
    #pragma unroll 16
    for (int j=0;j<64;j++){
      float sj = __shfl(s, j);
      rank += (sj > s) || (sj == s && j < lane);
    }
    float m = (rank < cnt) ? s : 0.0f;   // dropped entries become 0.0 (not -inf)
    float mx = m;
    #pragma unroll
    for (int off=32; off; off>>=1) mx = fmaxf(mx, __shfl_xor(mx, off));
    float e = __expf(m - mx);
    float sum = e;
    #pragma unroll
    for (int off=32; off; off>>=1) sum += __shfl_xor(sum, off);
    Ps[row*72 + lane] = f2b(e/sum);
  }
  __syncthreads();

  // O = P @ V ; wave w owns output cols 32w..32w+31
  f32x4 oacc[4][2] = {};
  #pragma unroll
  for (int ks=0; ks<2; ks++){
    short8 bv[2];
    #pragma unroll
    for (int jj=0; jj<2; jj++){
      int n = (w*2+jj)*16 + l16;
      short8 x;
      #pragma unroll
      for (int j=0;j<8;j++){
        int k = ks*32 + quad*8 + j;
        x[j] = (short)QV[k*136 + n];   // V in [k][n] layout
      }
      bv[jj] = x;
    }
    #pragma unroll
    for (int mt=0; mt<4; mt++){
      short8 aP = *(const short8*)(&Ps[(mt*16 + l16)*72 + ks*32 + quad*8]);
      #pragma unroll
      for (int jj=0; jj<2; jj++)
        oacc[mt][jj] = MFMA_BF16(aP, bv[jj], oacc[mt][jj]);
    }
  }
  #pragma unroll
  for (int mt=0; mt<4; mt++)
    #pragma unroll
    for (int jj=0; jj<2; jj++){
      int row = mt*16 + quad*4;
      int col = (w*2+jj)*16 + l16;
      #pragma unroll
      for (int r=0;r<4;r++)
        O[base + (size_t)(row+r)*HIDN + col] = f2b(oacc[mt][jj][r]);
    }
}

// ---------------- launch ----------------
extern "C" void kernel_launch(void* const* d_in, const int* in_sizes, int n_in,
                              void* d_out, int out_size, void* d_ws, size_t ws_size,
                              hipStream_t stream) {
  const float* hs = (const float*)d_in[0];
  const float* Wq = (const float*)d_in[1];
  const float* Wk = (const float*)d_in[2];
  const float* Wv = (const float*)d_in[3];
  const float* Wo = (const float*)d_in[4];
  const float* Wr = (const float*)d_in[5];
  const float* br = (const float*)d_in[6];
  float* out = (float*)d_out;
  char* ws = (char*)d_ws;

  const size_t MB = 1024u*1024u;
  float*    part   = (float*)(ws + 0);                 // 512 KB
  int*      counts = (int*)(ws + 512u*1024u);          // 64 B
  ushort_t* hsB    = (ushort_t*)(ws + 1*MB);           // 32 MB bf16 hidden
  ushort_t* WqT    = (ushort_t*)(ws + 33*MB);          // 8 MB each
  ushort_t* WkT    = (ushort_t*)(ws + 41*MB);
  ushort_t* WvT    = (ushort_t*)(ws + 49*MB);
  ushort_t* WoT    = (ushort_t*)(ws + 57*MB);
  ushort_t* Qm     = (ushort_t*)(ws + 65*MB);          // 32 MB each
  ushort_t* Km     = (ushort_t*)(ws + 97*MB);
  ushort_t* Vm     = (ushort_t*)(ws + 129*MB);         // ends at 161 MB
  ushort_t* AO     = Qm;                               // alias (safe, see bsa_attn)

  bsa_convert  <<<8192,           256, 0, stream>>>(hs, hsB);
  bsa_partial  <<<dim3(8,32,2),   256, 0, stream>>>(hs, part);
  bsa_router   <<<1,              256, 0, stream>>>(part, Wr, br, counts);
  bsa_transpose<<<dim3(32,32,4),  256, 0, stream>>>(Wq,Wk,Wv,Wo, WqT,WkT,WvT,WoT);
  bsa_gemm_bt<0><<<dim3(16,64),   256, 0, stream>>>(hsB, WqT, (void*)Qm, MTOT, 2048, 2048);
  bsa_gemm_bt<0><<<dim3(16,64),   256, 0, stream>>>(hsB, WkT, (void*)Km, MTOT, 2048, 2048);
  bsa_gemm_bt<0><<<dim3(16,64),   256, 0, stream>>>(hsB, WvT, (void*)Vm, MTOT, 2048, 2048);
  bsa_attn     <<<2048,           256, 0, stream>>>(Qm, Km, Vm, counts, AO);
  bsa_gemm_bt<1><<<dim3(16,64),   256, 0, stream>>>(AO, WoT, (void*)out, MTOT, 2048, 2048);
}

// Round 3
// 780.790 us; speedup vs baseline: 1.2238x; 1.2238x over previous
//
#include <hip/hip_runtime.h>
#include <hip/hip_bf16.h>
#include <cstdint>
#include <cstddef>

// ---- problem constants ----
#define B_   2
#define S_   4096
#define HIDN 2048
#define H_   16
#define D_   128
#define NB_  64
#define MTOT 8192              // B_*S_
#define QKVN 6144              // merged QKV row stride
#define SCALE_ 0.08838834764831845f   // 128^-0.5

typedef unsigned short ushort_t;
typedef __attribute__((ext_vector_type(8))) short short8;
typedef __attribute__((ext_vector_type(8))) ushort_t ushort8;
typedef __attribute__((ext_vector_type(4))) float f32x4;

__device__ inline float b2f(ushort_t x){ union{unsigned u; float f;} v; v.u=((unsigned)x)<<16; return v.f; }
__device__ inline ushort_t f2b(float f){ union{unsigned u; float f;} v; v.f=f; unsigned r=(v.u + 0x7FFF + ((v.u>>16)&1))>>16; return (ushort_t)r; }

#define MFMA_BF16(a,b,c) __builtin_amdgcn_mfma_f32_16x16x32_bf16((a),(b),(c),0,0,0)

// async global->LDS, 16B per lane. LDS dest = wave-uniform base + lane*16.
__device__ inline void async16(const ushort_t* g, ushort_t* l){
  __builtin_amdgcn_global_load_lds(
      (const __attribute__((address_space(1))) void*)g,
      (__attribute__((address_space(3))) void*)l, 16, 0, 0);
}

// ---------------- fp32 -> bf16 bulk convert (8 elts/thread) ----------------
__global__ void bsa_convert(const float* __restrict__ x, ushort_t* __restrict__ y){
  size_t i = ((size_t)blockIdx.x*256 + threadIdx.x)*8;
  float4 v0 = *(const float4*)(x+i);
  float4 v1 = *(const float4*)(x+i+4);
  ushort8 o;
  o[0]=f2b(v0.x); o[1]=f2b(v0.y); o[2]=f2b(v0.z); o[3]=f2b(v0.w);
  o[4]=f2b(v1.x); o[5]=f2b(v1.y); o[6]=f2b(v1.z); o[7]=f2b(v1.w);
  *(ushort8*)(y+i) = o;
}

// ---------------- router stage 1: partial column sums over S (fp32 in) ------
// grid (8, 32, 2), block 256. part[(b*32+sc)*HIDN + c] = sum of 128 rows.
__global__ void bsa_partial(const float* __restrict__ hs, float* __restrict__ part){
  int t = threadIdx.x;
  int c = blockIdx.x*256 + t;
  int sc = blockIdx.y;
  int b  = blockIdx.z;
  const float* p = hs + ((size_t)b*S_ + (size_t)sc*128)*HIDN + c;
  float s = 0.f;
  #pragma unroll 8
  for (int i=0;i<128;i++) s += p[(size_t)i*HIDN];
  part[((b*32+sc)*HIDN)+c] = s;
}

// ---------------- router stage 2, single block (all fp32) ----------------
__global__ void bsa_router(const float* __restrict__ part, const float* __restrict__ Wr,
                           const float* __restrict__ br, int* __restrict__ counts){
  __shared__ float cm[2*HIDN];    // 16 KB column means
  __shared__ float sig[2*H_];
  int t = threadIdx.x;
  for (int i=t; i<2*HIDN; i+=256){
    int b = i>>11, c = i&(HIDN-1);
    float s=0.f;
    for (int j=0;j<32;j++) s += part[((b*32+j)*HIDN)+c];
    cm[b*HIDN+c] = s * (1.0f/S_);
  }
  __syncthreads();
  {
    int g = t>>3;        // 0..31 = b*16+h
    int sl = t&7;
    int b = g>>4, h = g&15;
    float acc = 0.f;
    for (int c=sl; c<HIDN; c+=8) acc += cm[b*HIDN+c]*Wr[c*H_+h];
    acc += __shfl_xor(acc, 4);
    acc += __shfl_xor(acc, 2);
    acc += __shfl_xor(acc, 1);
    if (sl==0) sig[g] = 1.f/(1.f+expf(-(acc + br[h])));
  }
  __syncthreads();
  if (t < H_){
    float score = 0.5f*(sig[t] + sig[H_+t]);
    float eff = 0.5f*(1.0f - score*0.5f);
    int ac = (int)floorf(64.f*eff);
    if (ac < 1) ac = 1;
    counts[t] = ac;
  }
}

// ------------- weight transpose+convert: fp32 [K,N] -> bf16 [N,K] -----------
// grid (32,32,4), block 256
__global__ void bsa_transpose(const float* w0, const float* w1, const float* w2, const float* w3,
                              ushort_t* o0, ushort_t* o1, ushort_t* o2, ushort_t* o3){
  const float* src; ushort_t* dst;
  switch(blockIdx.z){
    case 0: src=w0; dst=o0; break;
    case 1: src=w1; dst=o1; break;
    case 2: src=w2; dst=o2; break;
    default: src=w3; dst=o3; break;
  }
  __shared__ ushort_t tile[64*72];   // pad 72 to break bank alignment
  int t = threadIdx.x;
  int r0 = blockIdx.y*64, c0 = blockIdx.x*64;
  for (int it=0; it<16; it++){
    int f = it*256 + t;
    int r = f>>6, c = f&63;
    tile[r*72+c] = f2b(src[(size_t)(r0+r)*HIDN + (c0+c)]);
  }
  __syncthreads();
  for (int it=0; it<16; it++){
    int f = it*256 + t;
    int cc = f>>6, rr = f&63;
    dst[(size_t)(c0+cc)*HIDN + (r0+rr)] = tile[rr*72+cc];
  }
}

// ---------------- m97-style bf16 GEMM: C[M,N] = A[M,K] @ BT[N,K]^T ----------
// 128x128 tile, BK=32, 256 threads = 4 waves (2x2), each wave 4x4 frags of 16x16x32.
// F32OUT: store fp32 accumulator directly; else round to bf16.
template<int F32OUT>
__global__ __launch_bounds__(256) void bsa_gemm_bt(const ushort_t* __restrict__ A,
                                                   const ushort_t* __restrict__ BT,
                                                   void* __restrict__ Cv,
                                                   int M, int N, int K){
  __shared__ __align__(16) ushort_t As[128*32];   // [row][k] 64B rows
  __shared__ __align__(16) ushort_t Bs[128*32];
  int t = threadIdx.x;
  int w = t>>6, lane = t&63;
  int wr = w>>1, wc = w&1;
  int quad = lane>>4, l16 = lane&15;
  int m0 = blockIdx.y*128, n0 = blockIdx.x*128;

  f32x4 acc[4][4] = {};

  // staging: chunk = w*2+i; lane covers LDS elems chunk*512 + lane*8
  // = row (chunk*16 + lane/4), col (lane&3)*8  in the [128][32] tile
  int srow = (w*2)*16 + (lane>>2);
  int scol = (lane&3)*8;

  for (int k0=0; k0<K; k0+=32){
    #pragma unroll
    for (int i=0;i<2;i++){
      int chunk = w*2+i;
      const ushort_t* ga = A  + (size_t)(m0 + srow + i*16)*K + k0 + scol;
      const ushort_t* gb = BT + (size_t)(n0 + srow + i*16)*K + k0 + scol;
      async16(ga, &As[chunk*512]);
      async16(gb, &Bs[chunk*512]);
    }
    __syncthreads();
    short8 a[4], b[4];
    #pragma unroll
    for (int i=0;i<4;i++)
      a[i] = *(const short8*)(&As[(wr*64 + i*16 + l16)*32 + quad*8]);
    #pragma unroll
    for (int j=0;j<4;j++)
      b[j] = *(const short8*)(&Bs[(wc*64 + j*16 + l16)*32 + quad*8]);
    #pragma unroll
    for (int i=0;i<4;i++)
      #pragma unroll
      for (int j=0;j<4;j++)
        acc[i][j] = MFMA_BF16(a[i], b[j], acc[i][j]);
    __syncthreads();
  }

  #pragma unroll
  for (int i=0;i<4;i++)
    #pragma unroll
    for (int j=0;j<4;j++){
      int m = m0 + wr*64 + i*16 + quad*4;
      int n = n0 + wc*64 + j*16 + l16;
      #pragma unroll
      for (int r=0;r<4;r++){
        if (F32OUT) ((float*)Cv)[(size_t)(m+r)*N + n] = acc[i][j][r];
        else        ((ushort_t*)Cv)[(size_t)(m+r)*N + n] = f2b(acc[i][j][r]);
      }
    }
}

// ---------------- block-diagonal top-k attention ----------------
// grid 2048 = B*H*NB, block 256 (4 waves). QKV merged [8192][6144].
// LDS overlays: regA = Q then Sc(fp32 64x68); regB = K then V. 44032 B -> 3 blk/CU.
// Top-k via 64-lane bitonic sort (values) + ballot tie-handling: identical
// keep-set to stable descending argsort rank (ties by ascending index).
__global__ __launch_bounds__(256) void bsa_attn(const ushort_t* __restrict__ QKV,
                                                const int* __restrict__ counts,
                                                ushort_t* __restrict__ O){
  __shared__ __align__(16) ushort_t regA[64*136];  // 17408 B: Q, then Sc overlay
  __shared__ __align__(16) ushort_t regB[64*136];  // 17408 B: K, then V
  __shared__ __align__(16) ushort_t Ps[64*72];     // 9216 B
  float* Sc = (float*)regA;                        // stride 68 floats

  int t = threadIdx.x, w = t>>6, lane = t&63, quad = lane>>4, l16 = lane&15;
  int bid = blockIdx.x;
  int b  = bid>>10;
  int h  = (bid>>6)&15;
  int nb = bid&63;
  size_t qbase = ((size_t)b*S_ + (size_t)nb*64)*QKVN + (size_t)h*D_;
  size_t obase = ((size_t)b*S_ + (size_t)nb*64)*HIDN + (size_t)h*D_;

  // stage Q -> regA, K -> regB
  #pragma unroll
  for (int it=0; it<4; it++){
    int f = it*256 + t;            // 0..1023, 8 bf16 each
    int r = f>>4, c = (f&15)*8;
    *(int4*)(&regA[r*136+c]) = *(const int4*)(QKV + qbase +        (size_t)r*QKVN + c);
    *(int4*)(&regB[r*136+c]) = *(const int4*)(QKV + qbase + 2048 + (size_t)r*QKVN + c);
  }
  __syncthreads();

  // S = Q K^T * scale ; wave w owns query rows 16w..16w+15
  f32x4 sacc[4] = {};
  #pragma unroll
  for (int ks=0; ks<4; ks++){
    short8 afr = *(const short8*)(&regA[(w*16 + l16)*136 + ks*32 + quad*8]);
    #pragma unroll
    for (int nt=0; nt<4; nt++){
      short8 bfr = *(const short8*)(&regB[(nt*16 + l16)*136 + ks*32 + quad*8]);
      sacc[nt] = MFMA_BF16(afr, bfr, sacc[nt]);
    }
  }
  __syncthreads();   // all Q/K LDS reads complete before overwrite

  // Sc (own rows) into regA overlay; stage V into regB
  #pragma unroll
  for (int nt=0; nt<4; nt++)
    #pragma unroll
    for (int r=0;r<4;r++)
      Sc[(w*16 + quad*4 + r)*68 + nt*16 + l16] = sacc[nt][r]*SCALE_;
  #pragma unroll
  for (int it=0; it<4; it++){
    int f = it*256 + t;
    int r = f>>4, c = (f&15)*8;
    *(int4*)(&regB[r*136+c]) = *(const int4*)(QKV + qbase + 4096 + (size_t)r*QKVN + c);
  }
  __syncthreads();

  // top-k + softmax; 4 rows at a time for shfl-chain ILP
  int cnt = counts[h];
  for (int g=0; g<4; g++){
    float s[4], v[4];
    #pragma unroll
    for (int rr=0; rr<4; rr++){
      s[rr] = Sc[(w*16 + g*4 + rr)*68 + lane];
      v[rr] = s[rr];
    }
    // bitonic sort ascending across 64 lanes (values only), 4-wide ILP
    #pragma unroll
    for (int k=2; k<=64; k<<=1){
      #pragma unroll
      for (int m=k>>1; m>=1; m>>=1){
        #pragma unroll
        for (int rr=0; rr<4; rr++){
          float o = __shfl_xor(v[rr], m);
          bool keepMin = (((lane & k)==0) == ((lane & m)==0));
          float lo = fminf(v[rr], o), hi = fmaxf(v[rr], o);
          v[rr] = keepMin ? lo : hi;
        }
      }
    }
    #pragma unroll
    for (int rr=0; rr<4; rr++){
      float T = __shfl(v[rr], 64 - cnt);                 // cnt-th largest
      unsigned long long gt = __ballot(s[rr] > T);
      unsigned long long eq = __ballot(s[rr] == T);
      int G = __popcll(gt);
      int eqr = __popcll(eq & ((1ull<<lane)-1ull));
      bool keep = (s[rr] > T) || ((s[rr] == T) && (eqr < cnt - G));
      float m = keep ? s[rr] : 0.0f;                     // dropped -> 0.0 (not -inf)
      float mx = fmaxf(__shfl(v[rr], 63), 0.0f);         // max kept = global max; zeros present
      float e = __expf(m - mx);
      float sum = e;
      #pragma unroll
      for (int off=32; off; off>>=1) sum += __shfl_xor(sum, off);
      Ps[(w*16 + g*4 + rr)*72 + lane] = f2b(e/sum);
    }
  }
  __syncthreads();

  // O = P @ V ; wave w owns output cols 32w..32w+31
  f32x4 oacc[4][2] = {};
  #pragma unroll
  for (int ks=0; ks<2; ks++){
    short8 bv[2];
    #pragma unroll
    for (int jj=0; jj<2; jj++){
      int n = (w*2+jj)*16 + l16;
      short8 x;
      #pragma unroll
      for (int j=0;j<8;j++){
        int k = ks*32 + quad*8 + j;
        x[j] = (short)regB[k*136 + n];   // V in [k][n] layout
      }
      bv[jj] = x;
    }
    #pragma unroll
    for (int mt=0; mt<4; mt++){
      short8 aP = *(const short8*)(&Ps[(mt*16 + l16)*72 + ks*32 + quad*8]);
      #pragma unroll
      for (int jj=0; jj<2; jj++)
        oacc[mt][jj] = MFMA_BF16(aP, bv[jj], oacc[mt][jj]);
    }
  }
  #pragma unroll
  for (int mt=0; mt<4; mt++)
    #pragma unroll
    for (int jj=0; jj<2; jj++){
      int row = mt*16 + quad*4;
      int col = (w*2+jj)*16 + l16;
      #pragma unroll
      for (int r=0;r<4;r++)
        O[obase + (size_t)(row+r)*HIDN + col] = f2b(oacc[mt][jj][r]);
    }
}

// ---------------- launch ----------------
extern "C" void kernel_launch(void* const* d_in, const int* in_sizes, int n_in,
                              void* d_out, int out_size, void* d_ws, size_t ws_size,
                              hipStream_t stream) {
  const float* hs = (const float*)d_in[0];
  const float* Wq = (const float*)d_in[1];
  const float* Wk = (const float*)d_in[2];
  const float* Wv = (const float*)d_in[3];
  const float* Wo = (const float*)d_in[4];
  const float* Wr = (const float*)d_in[5];
  const float* br = (const float*)d_in[6];
  float* out = (float*)d_out;
  char* ws = (char*)d_ws;

  const size_t MB = 1024u*1024u;
  float*    part   = (float*)(ws + 0);                 // 512 KB
  int*      counts = (int*)(ws + 512u*1024u);          // 64 B
  ushort_t* hsB    = (ushort_t*)(ws + 1*MB);           // 32 MB bf16 hidden
  ushort_t* WqT    = (ushort_t*)(ws + 33*MB);          // 8 MB each; q|k|v contiguous
  ushort_t* WkT    = (ushort_t*)(ws + 41*MB);
  ushort_t* WvT    = (ushort_t*)(ws + 49*MB);
  ushort_t* WoT    = (ushort_t*)(ws + 57*MB);
  ushort_t* QKV    = (ushort_t*)(ws + 65*MB);          // 96 MB: [8192][6144]
  ushort_t* AO     = hsB;   // alias: hsB dead after the QKV GEMM

  bsa_convert   <<<8192,          256, 0, stream>>>(hs, hsB);
  bsa_partial   <<<dim3(8,32,2),  256, 0, stream>>>(hs, part);
  bsa_router    <<<1,             256, 0, stream>>>(part, Wr, br, counts);
  bsa_transpose <<<dim3(32,32,4), 256, 0, stream>>>(Wq,Wk,Wv,Wo, WqT,WkT,WvT,WoT);
  // merged QKV projection: BT = [WqT|WkT|WvT] rows 0..6143; 3072 blocks = 4x768 (no tail)
  bsa_gemm_bt<0><<<dim3(48,64),   256, 0, stream>>>(hsB, WqT, (void*)QKV, MTOT, QKVN, 2048);
  bsa_attn      <<<2048,          256, 0, stream>>>(QKV, counts, AO);
  bsa_gemm_bt<1><<<dim3(16,64),   256, 0, stream>>>(AO, WoT, (void*)out, MTOT, 2048, 2048);
}

// Round 4
// 713.956 us; speedup vs baseline: 1.3383x; 1.0936x over previous
//
#include <hip/hip_runtime.h>
#include <hip/hip_bf16.h>
#include <cstdint>
#include <cstddef>

// ---- problem constants ----
#define B_   2
#define S_   4096
#define HIDN 2048
#define H_   16
#define D_   128
#define NB_  64
#define MTOT 8192              // B_*S_
#define QKVN 6144              // merged QKV row stride
#define SCALE_ 0.08838834764831845f   // 128^-0.5

typedef unsigned short ushort_t;
typedef __attribute__((ext_vector_type(8))) short short8;
typedef __attribute__((ext_vector_type(8))) ushort_t ushort8;
typedef __attribute__((ext_vector_type(4))) float f32x4;

__device__ inline float b2f(ushort_t x){ union{unsigned u; float f;} v; v.u=((unsigned)x)<<16; return v.f; }
__device__ inline ushort_t f2b(float f){ union{unsigned u; float f;} v; v.f=f; unsigned r=(v.u + 0x7FFF + ((v.u>>16)&1))>>16; return (ushort_t)r; }

#define MFMA_BF16(a,b,c) __builtin_amdgcn_mfma_f32_16x16x32_bf16((a),(b),(c),0,0,0)

// async global->LDS, 16B per lane. LDS dest = wave-uniform base + lane*16.
__device__ inline void async16(const ushort_t* g, ushort_t* l){
  __builtin_amdgcn_global_load_lds(
      (const __attribute__((address_space(1))) void*)g,
      (__attribute__((address_space(3))) void*)l, 16, 0, 0);
}

// ------- fused fp32->bf16 convert + router partial column sums ----------
// grid (4,32,2), block 256. Thread owns 2 cols; rows sc*128..sc*128+127.
// Partial-sum order (sequential over the 128 rows) identical to previous
// bsa_partial -> bit-exact.
__global__ void bsa_convpart(const float* __restrict__ hs, ushort_t* __restrict__ hsB,
                             float* __restrict__ part){
  int t = threadIdx.x;
  int c  = blockIdx.x*512 + t*2;
  int sc = blockIdx.y;
  int b  = blockIdx.z;
  const float* p = hs  + ((size_t)b*S_ + (size_t)sc*128)*HIDN + c;
  ushort_t*    q = hsB + ((size_t)b*S_ + (size_t)sc*128)*HIDN + c;
  float s0=0.f, s1=0.f;
  #pragma unroll 8
  for (int i=0;i<128;i++){
    float2 v = *(const float2*)(p + (size_t)i*HIDN);
    s0 += v.x; s1 += v.y;
    unsigned pk = (unsigned)f2b(v.x) | ((unsigned)f2b(v.y)<<16);
    *(unsigned*)(q + (size_t)i*HIDN) = pk;
  }
  part[((b*32+sc)*HIDN)+c]   = s0;
  part[((b*32+sc)*HIDN)+c+1] = s1;
}

// ---------------- router stage 2, single block (all fp32) ----------------
__global__ void bsa_router(const float* __restrict__ part, const float* __restrict__ Wr,
                           const float* __restrict__ br, int* __restrict__ counts){
  __shared__ float cm[2*HIDN];    // 16 KB column means
  __shared__ float sig[2*H_];
  int t = threadIdx.x;
  for (int i=t; i<2*HIDN; i+=256){
    int b = i>>11, c = i&(HIDN-1);
    float s=0.f;
    for (int j=0;j<32;j++) s += part[((b*32+j)*HIDN)+c];
    cm[b*HIDN+c] = s * (1.0f/S_);
  }
  __syncthreads();
  {
    int g = t>>3;        // 0..31 = b*16+h
    int sl = t&7;
    int b = g>>4, h = g&15;
    float acc = 0.f;
    for (int c=sl; c<HIDN; c+=8) acc += cm[b*HIDN+c]*Wr[c*H_+h];
    acc += __shfl_xor(acc, 4);
    acc += __shfl_xor(acc, 2);
    acc += __shfl_xor(acc, 1);
    if (sl==0) sig[g] = 1.f/(1.f+expf(-(acc + br[h])));
  }
  __syncthreads();
  if (t < H_){
    float score = 0.5f*(sig[t] + sig[H_+t]);
    float eff = 0.5f*(1.0f - score*0.5f);
    int ac = (int)floorf(64.f*eff);
    if (ac < 1) ac = 1;
    counts[t] = ac;
  }
}

// ------------- weight transpose+convert: fp32 [K,N] -> bf16 [N,K] -----------
// grid (32,32,4), block 256
__global__ void bsa_transpose(const float* w0, const float* w1, const float* w2, const float* w3,
                              ushort_t* o0, ushort_t* o1, ushort_t* o2, ushort_t* o3){
  const float* src; ushort_t* dst;
  switch(blockIdx.z){
    case 0: src=w0; dst=o0; break;
    case 1: src=w1; dst=o1; break;
    case 2: src=w2; dst=o2; break;
    default: src=w3; dst=o3; break;
  }
  __shared__ ushort_t tile[64*72];   // pad 72 to break bank alignment
  int t = threadIdx.x;
  int r0 = blockIdx.y*64, c0 = blockIdx.x*64;
  for (int it=0; it<16; it++){
    int f = it*256 + t;
    int r = f>>6, c = f&63;
    tile[r*72+c] = f2b(src[(size_t)(r0+r)*HIDN + (c0+c)]);
  }
  __syncthreads();
  for (int it=0; it<16; it++){
    int f = it*256 + t;
    int cc = f>>6, rr = f&63;
    dst[(size_t)(c0+cc)*HIDN + (r0+rr)] = tile[rr*72+cc];
  }
}

// ---------------- m97-style bf16 GEMM: C[M,N] = A[M,K] @ BT[N,K]^T ----------
// 128x128 tile, BK=32, 256 threads = 4 waves (2x2), each wave 4x4 frags of 16x16x32.
// F32OUT: store fp32 accumulator directly; else round to bf16.
// MINW=4: force 4 blocks/CU (reg budget 128/wave incl. 64 AGPR acc).
template<int F32OUT, int MINW>
__global__ __launch_bounds__(256, MINW) void bsa_gemm_bt(const ushort_t* __restrict__ A,
                                                   const ushort_t* __restrict__ BT,
                                                   void* __restrict__ Cv,
                                                   int M, int N, int K){
  __shared__ __align__(16) ushort_t As[128*32];   // [row][k] 64B rows
  __shared__ __align__(16) ushort_t Bs[128*32];
  int t = threadIdx.x;
  int w = t>>6, lane = t&63;
  int wr = w>>1, wc = w&1;
  int quad = lane>>4, l16 = lane&15;
  int m0 = blockIdx.y*128, n0 = blockIdx.x*128;

  f32x4 acc[4][4] = {};

  // staging: chunk = w*2+i; lane covers LDS elems chunk*512 + lane*8
  // = row (chunk*16 + lane/4), col (lane&3)*8  in the [128][32] tile
  int srow = (w*2)*16 + (lane>>2);
  int scol = (lane&3)*8;

  for (int k0=0; k0<K; k0+=32){
    #pragma unroll
    for (int i=0;i<2;i++){
      int chunk = w*2+i;
      const ushort_t* ga = A  + (size_t)(m0 + srow + i*16)*K + k0 + scol;
      const ushort_t* gb = BT + (size_t)(n0 + srow + i*16)*K + k0 + scol;
      async16(ga, &As[chunk*512]);
      async16(gb, &Bs[chunk*512]);
    }
    __syncthreads();
    short8 a[4], b[4];
    #pragma unroll
    for (int i=0;i<4;i++)
      a[i] = *(const short8*)(&As[(wr*64 + i*16 + l16)*32 + quad*8]);
    #pragma unroll
    for (int j=0;j<4;j++)
      b[j] = *(const short8*)(&Bs[(wc*64 + j*16 + l16)*32 + quad*8]);
    #pragma unroll
    for (int i=0;i<4;i++)
      #pragma unroll
      for (int j=0;j<4;j++)
        acc[i][j] = MFMA_BF16(a[i], b[j], acc[i][j]);
    __syncthreads();
  }

  #pragma unroll
  for (int i=0;i<4;i++)
    #pragma unroll
    for (int j=0;j<4;j++){
      int m = m0 + wr*64 + i*16 + quad*4;
      int n = n0 + wc*64 + j*16 + l16;
      #pragma unroll
      for (int r=0;r<4;r++){
        if (F32OUT) ((float*)Cv)[(size_t)(m+r)*N + n] = acc[i][j][r];
        else        ((ushort_t*)Cv)[(size_t)(m+r)*N + n] = f2b(acc[i][j][r]);
      }
    }
}

// ---------------- block-diagonal top-k attention ----------------
// grid 2048 = B*H*NB, block 256 (4 waves). QKV merged [8192][6144].
// LDS overlays: regA = Q then Sc(fp32 64x68); regB = K then V. 44032 B -> 3 blk/CU.
// V prefetched into registers at kernel start (latency hidden under staging+QK).
// Sort reads only own-wave Sc rows -> no barrier between Sc write and sort.
__global__ __launch_bounds__(256) void bsa_attn(const ushort_t* __restrict__ QKV,
                                                const int* __restrict__ counts,
                                                ushort_t* __restrict__ O){
  __shared__ __align__(16) ushort_t regA[64*136];  // 17408 B: Q, then Sc overlay
  __shared__ __align__(16) ushort_t regB[64*136];  // 17408 B: K, then V
  __shared__ __align__(16) ushort_t Ps[64*72];     // 9216 B
  float* Sc = (float*)regA;                        // stride 68 floats

  int t = threadIdx.x, w = t>>6, lane = t&63, quad = lane>>4, l16 = lane&15;
  int bid = blockIdx.x;
  int b  = bid>>10;
  int h  = (bid>>6)&15;
  int nb = bid&63;
  size_t qbase = ((size_t)b*S_ + (size_t)nb*64)*QKVN + (size_t)h*D_;
  size_t obase = ((size_t)b*S_ + (size_t)nb*64)*HIDN + (size_t)h*D_;

  // prefetch V into registers (consumed after B2)
  int4 vre[4];
  #pragma unroll
  for (int it=0; it<4; it++){
    int f = it*256 + t;
    int r = f>>4, c = (f&15)*8;
    vre[it] = *(const int4*)(QKV + qbase + 4096 + (size_t)r*QKVN + c);
  }

  // stage Q -> regA, K -> regB
  #pragma unroll
  for (int it=0; it<4; it++){
    int f = it*256 + t;            // 0..1023, 8 bf16 each
    int r = f>>4, c = (f&15)*8;
    *(int4*)(&regA[r*136+c]) = *(const int4*)(QKV + qbase +        (size_t)r*QKVN + c);
    *(int4*)(&regB[r*136+c]) = *(const int4*)(QKV + qbase + 2048 + (size_t)r*QKVN + c);
  }
  __syncthreads();   // B1

  // S = Q K^T * scale ; wave w owns query rows 16w..16w+15
  f32x4 sacc[4] = {};
  #pragma unroll
  for (int ks=0; ks<4; ks++){
    short8 afr = *(const short8*)(&regA[(w*16 + l16)*136 + ks*32 + quad*8]);
    #pragma unroll
    for (int nt=0; nt<4; nt++){
      short8 bfr = *(const short8*)(&regB[(nt*16 + l16)*136 + ks*32 + quad*8]);
      sacc[nt] = MFMA_BF16(afr, bfr, sacc[nt]);
    }
  }
  __syncthreads();   // B2: all Q/K LDS reads complete before overwrite

  // Sc (own rows) into regA overlay; V registers -> regB
  #pragma unroll
  for (int nt=0; nt<4; nt++)
    #pragma unroll
    for (int r=0;r<4;r++)
      Sc[(w*16 + quad*4 + r)*68 + nt*16 + l16] = sacc[nt][r]*SCALE_;
  #pragma unroll
  for (int it=0; it<4; it++){
    int f = it*256 + t;
    int r = f>>4, c = (f&15)*8;
    *(int4*)(&regB[r*136+c]) = vre[it];
  }

  // top-k + softmax on own-wave rows (no barrier needed: Sc rows are ours)
  int cnt = counts[h];
  for (int g=0; g<4; g++){
    float s[4], v[4];
    #pragma unroll
    for (int rr=0; rr<4; rr++){
      s[rr] = Sc[(w*16 + g*4 + rr)*68 + lane];
      v[rr] = s[rr];
    }
    // bitonic sort ascending across 64 lanes (values only), 4-wide ILP
    #pragma unroll
    for (int k=2; k<=64; k<<=1){
      #pragma unroll
      for (int m=k>>1; m>=1; m>>=1){
        #pragma unroll
        for (int rr=0; rr<4; rr++){
          float o = __shfl_xor(v[rr], m);
          bool keepMin = (((lane & k)==0) == ((lane & m)==0));
          float lo = fminf(v[rr], o), hi = fmaxf(v[rr], o);
          v[rr] = keepMin ? lo : hi;
        }
      }
    }
    #pragma unroll
    for (int rr=0; rr<4; rr++){
      float T = __shfl(v[rr], 64 - cnt);                 // cnt-th largest
      unsigned long long gt = __ballot(s[rr] > T);
      unsigned long long eq = __ballot(s[rr] == T);
      int G = __popcll(gt);
      int eqr = __popcll(eq & ((1ull<<lane)-1ull));
      bool keep = (s[rr] > T) || ((s[rr] == T) && (eqr < cnt - G));
      float m = keep ? s[rr] : 0.0f;                     // dropped -> 0.0 (not -inf)
      float mx = fmaxf(__shfl(v[rr], 63), 0.0f);         // max kept = global max; zeros present
      float e = __expf(m - mx);
      float sum = e;
      #pragma unroll
      for (int off=32; off; off>>=1) sum += __shfl_xor(sum, off);
      Ps[(w*16 + g*4 + rr)*72 + lane] = f2b(e/sum);
    }
  }
  __syncthreads();   // B3: V writes + Ps visible to all

  // O = P @ V ; wave w owns output cols 32w..32w+31
  f32x4 oacc[4][2] = {};
  #pragma unroll
  for (int ks=0; ks<2; ks++){
    short8 bv[2];
    #pragma unroll
    for (int jj=0; jj<2; jj++){
      int n = (w*2+jj)*16 + l16;
      short8 x;
      #pragma unroll
      for (int j=0;j<8;j++){
        int k = ks*32 + quad*8 + j;
        x[j] = (short)regB[k*136 + n];   // V in [k][n] layout
      }
      bv[jj] = x;
    }
    #pragma unroll
    for (int mt=0; mt<4; mt++){
      short8 aP = *(const short8*)(&Ps[(mt*16 + l16)*72 + ks*32 + quad*8]);
      #pragma unroll
      for (int jj=0; jj<2; jj++)
        oacc[mt][jj] = MFMA_BF16(aP, bv[jj], oacc[mt][jj]);
    }
  }
  #pragma unroll
  for (int mt=0; mt<4; mt++)
    #pragma unroll
    for (int jj=0; jj<2; jj++){
      int row = mt*16 + quad*4;
      int col = (w*2+jj)*16 + l16;
      #pragma unroll
      for (int r=0;r<4;r++)
        O[obase + (size_t)(row+r)*HIDN + col] = f2b(oacc[mt][jj][r]);
    }
}

// ---------------- launch ----------------
extern "C" void kernel_launch(void* const* d_in, const int* in_sizes, int n_in,
                              void* d_out, int out_size, void* d_ws, size_t ws_size,
                              hipStream_t stream) {
  const float* hs = (const float*)d_in[0];
  const float* Wq = (const float*)d_in[1];
  const float* Wk = (const float*)d_in[2];
  const float* Wv = (const float*)d_in[3];
  const float* Wo = (const float*)d_in[4];
  const float* Wr = (const float*)d_in[5];
  const float* br = (const float*)d_in[6];
  float* out = (float*)d_out;
  char* ws = (char*)d_ws;

  const size_t MB = 1024u*1024u;
  float*    part   = (float*)(ws + 0);                 // 512 KB
  int*      counts = (int*)(ws + 512u*1024u);          // 64 B
  ushort_t* hsB    = (ushort_t*)(ws + 1*MB);           // 32 MB bf16 hidden
  ushort_t* WqT    = (ushort_t*)(ws + 33*MB);          // 8 MB each; q|k|v contiguous
  ushort_t* WkT    = (ushort_t*)(ws + 41*MB);
  ushort_t* WvT    = (ushort_t*)(ws + 49*MB);
  ushort_t* WoT    = (ushort_t*)(ws + 57*MB);
  ushort_t* QKV    = (ushort_t*)(ws + 65*MB);          // 96 MB: [8192][6144]
  ushort_t* AO     = hsB;   // alias: hsB dead after the QKV GEMM

  bsa_convpart  <<<dim3(4,32,2),  256, 0, stream>>>(hs, hsB, part);
  bsa_router    <<<1,             256, 0, stream>>>(part, Wr, br, counts);
  bsa_transpose <<<dim3(32,32,4), 256, 0, stream>>>(Wq,Wk,Wv,Wo, WqT,WkT,WvT,WoT);
  // merged QKV projection: BT = [WqT|WkT|WvT]; 3072 blocks = 3 full rounds of 1024
  bsa_gemm_bt<0,4><<<dim3(48,64), 256, 0, stream>>>(hsB, WqT, (void*)QKV, MTOT, QKVN, 2048);
  bsa_attn      <<<2048,          256, 0, stream>>>(QKV, counts, AO);
  // Wo projection: 1024 blocks = exactly 1 round at 4 blocks/CU
  bsa_gemm_bt<1,4><<<dim3(16,64), 256, 0, stream>>>(AO, WoT, (void*)out, MTOT, 2048, 2048);
}